// Round 5
// baseline (378.673 us; speedup 1.0000x reference)
//
#include <hip/hip_runtime.h>

#define DD     64      // channels
#define DBSH   7       // 128 dst nodes per bucket
#define DBN    128
#define GRSH   13      // src granule = 8192 nodes = 1 MB of bf16 rows (L2-window)
#define SCAP   256     // capacity per (dst-bucket, src-granule): mean 123 + 12 sigma
#define SCAPSH 8
#define ASTR   65      // LDS accumulator row stride (ints): 65%32=1 -> banks spread by dst
#define FIXS   262144.0f        // 2^18 fixed-point scale (native int ds_add; |sum|<1e8)
#define FIXI   (1.0f/262144.0f)

typedef unsigned int uint32;
typedef __attribute__((ext_vector_type(8))) short short8;   // 8 bf16 (4 VGPRs)
typedef __attribute__((ext_vector_type(4))) float f32x4;    // MFMA accumulator

__device__ __forceinline__ unsigned short f2bf_rne(float f) {
    uint32 u = __float_as_uint(f);
    u += 0x7fffu + ((u >> 16) & 1u);   // round-to-nearest-even
    return (unsigned short)(u >> 16);
}
__device__ __forceinline__ float bf_lo(uint32 w) { return __uint_as_float(w << 16); }
__device__ __forceinline__ float bf_hi(uint32 w) { return __uint_as_float(w & 0xffff0000u); }
__device__ __forceinline__ float bf2f(unsigned short s) {
    return __uint_as_float(((uint32)s) << 16);
}

// ===========================================================================
// x (fp32) -> bf16 shadow; zero the 10166 sub-bucket counters; build the
// bf16 W^T tables for all 3 layers (wtg[layer][c*128+k], k<64 Wl, k>=64 Wr).
// ===========================================================================
__global__ __launch_bounds__(256) void cvt_kernel(
    const float* __restrict__ x, unsigned short* __restrict__ xb, int n4,
    int* __restrict__ gCnt, int nbins,
    const float* __restrict__ Wl0, const float* __restrict__ Wr0,
    const float* __restrict__ Wl1, const float* __restrict__ Wr1,
    const float* __restrict__ Wl2, const float* __restrict__ Wr2,
    unsigned short* __restrict__ wtg) {
    const int gid = blockIdx.x * 256 + threadIdx.x;
    if (gid < nbins) gCnt[gid] = 0;
    if (gid < 3 * 2 * DD * DD) {              // 24576 W^T elements
        int layer = gid >> 13;
        int idx   = gid & 8191;
        int k = idx >> 6, c = idx & 63;
        const float* Wsrc;
        if (layer == 0)      Wsrc = (k < DD) ? Wl0 : Wr0;
        else if (layer == 1) Wsrc = (k < DD) ? Wl1 : Wr1;
        else                 Wsrc = (k < DD) ? Wl2 : Wr2;
        float v = Wsrc[(k & (DD - 1)) * DD + c];
        wtg[layer * 8192 + c * 128 + k] = f2bf_rne(v);
    }
    if (gid < n4) {
        float4 v = ((const float4*)x)[gid];
        ushort4 p;
        p.x = f2bf_rne(v.x); p.y = f2bf_rne(v.y);
        p.z = f2bf_rne(v.z); p.w = f2bf_rne(v.w);
        ((ushort4*)xb)[gid] = p;
    }
}

// ===========================================================================
// Bucket edges by composite key (dst>>7, src>>13): 782 x 13 = 10166 fixed-
// capacity sub-buckets. One global atomic per edge (~123 hits/counter, L2-
// resident counters). Sub-bucket order IS the src-granule sort the sweep
// kernel needs -- no separate sort pass, no CSR, no offsets.
// ===========================================================================
__global__ __launch_bounds__(1024) void bucket_kernel(const int* __restrict__ src,
                                                      const int* __restrict__ dst,
                                                      int* __restrict__ gCnt,
                                                      int2* __restrict__ buf,
                                                      int E, int ngr) {
    const int t  = threadIdx.x;
    const int e0 = blockIdx.x * 4096;
#pragma unroll
    for (int k = 0; k < 4; ++k) {
        int e = e0 + k * 1024 + t;
        if (e < E) {
            int d = dst[e];
            int s = src[e];
            int bid = (d >> DBSH) * ngr + (s >> GRSH);
            int rk = atomicAdd(&gCnt[bid], 1);
            if (rk < SCAP)                    // 12-sigma margin; protects memory
                buf[((size_t)bid << SCAPSH) + rk] = make_int2(s, d);
        }
    }
}

// ===========================================================================
// Phase-aligned sweep: one block per dst-bucket (128 nodes). All 782 blocks
// are co-resident (33.3 KB LDS -> 4 blocks/CU) and walk src-granules g=0..12
// in lockstep-ish order, so every XCD's L2 holds the current 1 MB src window
// -- the random 128 B row reads become L2 hits and the table streams through
// L3 once per XCD (was: 160 MB of uncorrelated random rows at ~3.3 TB/s,
// the measured floor of the dst-major gather).
// Accumulate in LDS fixed-point int (native ds_add, deterministic): x*2^18,
// |sum| <= maxdeg(~40) * 10 * 2^18 ~ 1e8 << 2^31; quantum 4e-6 << bf16 4e-3.
// Degrees counted in-pass (replaces CSR degrees). Emits bf16 mean rows.
// ===========================================================================
__global__ __launch_bounds__(256, 4) void sweep_mean(
    const unsigned short* __restrict__ hbin,  // [N,64] bf16 layer input
    const int2* __restrict__ buf,             // sub-bucketed (src,dst) pairs
    const int* __restrict__ gCnt,             // [nbins] sub-bucket counts
    unsigned short* __restrict__ mean,        // [N,64] bf16 out
    int N, int ngr) {
    __shared__ int acc[DBN * ASTR];           // 33280 B fixed-point sums
    __shared__ int sdeg[DBN];
    const int t = threadIdx.x;
    for (int i = t; i < DBN * ASTR; i += 256) acc[i] = 0;
    if (t < DBN) sdeg[t] = 0;
    __syncthreads();

    const int grp = t >> 3;                   // 32 edge slots
    const int q   = t & 7;                    // 16 B chunk within 128 B row
    const int b0  = blockIdx.x * ngr;
#pragma unroll 1
    for (int g = 0; g < ngr; ++g) {           // ascending src granule = the sweep
        const int bid = b0 + g;
        const int cnt = min(gCnt[bid], SCAP);
        const int2* eb = buf + ((size_t)bid << SCAPSH);
#pragma unroll 1
        for (int jb = 0; jb < cnt; jb += 128) {   // 4-deep batches, 128 edges/round
            int2 ed[4]; uint4 v[4]; bool val[4];
#pragma unroll
            for (int k = 0; k < 4; ++k) {
                int j = jb + k * 32 + grp;
                val[k] = (j < cnt);
                ed[k] = val[k] ? eb[j] : make_int2(0, 0);
            }
#pragma unroll
            for (int k = 0; k < 4; ++k)
                v[k] = val[k] ? ((const uint4*)(hbin + (size_t)ed[k].x * DD))[q]
                              : make_uint4(0u, 0u, 0u, 0u);
#pragma unroll
            for (int k = 0; k < 4; ++k) {
                if (val[k]) {
                    int dl = ed[k].y & (DBN - 1);
                    int* ap = &acc[dl * ASTR + q * 8];
                    atomicAdd(ap + 0, __float2int_rn(bf_lo(v[k].x) * FIXS));
                    atomicAdd(ap + 1, __float2int_rn(bf_hi(v[k].x) * FIXS));
                    atomicAdd(ap + 2, __float2int_rn(bf_lo(v[k].y) * FIXS));
                    atomicAdd(ap + 3, __float2int_rn(bf_hi(v[k].y) * FIXS));
                    atomicAdd(ap + 4, __float2int_rn(bf_lo(v[k].z) * FIXS));
                    atomicAdd(ap + 5, __float2int_rn(bf_hi(v[k].z) * FIXS));
                    atomicAdd(ap + 6, __float2int_rn(bf_lo(v[k].w) * FIXS));
                    atomicAdd(ap + 7, __float2int_rn(bf_hi(v[k].w) * FIXS));
                    if (q == 0) atomicAdd(&sdeg[dl], 1);
                }
            }
        }
    }
    __syncthreads();

    // write bf16 mean rows, coalesced 16 B chunks
    for (int i = t; i < DBN * 8; i += 256) {
        int row = i >> 3, qq = i & 7;
        int node = blockIdx.x * DBN + row;
        if (node < N) {
            float sc = FIXI / fmaxf((float)sdeg[row], 1.0f);
            const int* ap = &acc[row * ASTR + qq * 8];
            uint4 wv;
            wv.x = (uint32)f2bf_rne((float)ap[0] * sc) |
                   ((uint32)f2bf_rne((float)ap[1] * sc) << 16);
            wv.y = (uint32)f2bf_rne((float)ap[2] * sc) |
                   ((uint32)f2bf_rne((float)ap[3] * sc) << 16);
            wv.z = (uint32)f2bf_rne((float)ap[4] * sc) |
                   ((uint32)f2bf_rne((float)ap[5] * sc) << 16);
            wv.w = (uint32)f2bf_rne((float)ap[6] * sc) |
                   ((uint32)f2bf_rne((float)ap[7] * sc) << 16);
            *(uint4*)(mean + (size_t)node * DD + qq * 8) = wv;
        }
    }
}

// ===========================================================================
// Transform kernel: y = [mean||self] @ [Wl;Wr] + bl, then
//   MODE 0: hbout = bf16(relu(LN(y)) + self);  MODE 1: out = l2norm(y+self).
// Dense streaming, zero LDS, zero barriers (proven round 4).
// Block = 256 thr = 4 waves = 64 nodes. C/D: col=lane&15, row=quad*4+reg.
// ===========================================================================
template <int MODE>
__global__ __launch_bounds__(256, 4) void sage_xform(
    const unsigned short* __restrict__ hbin,  // [N,64] bf16 self
    const unsigned short* __restrict__ mean,  // [N,64] bf16 neighbor mean
    const unsigned short* __restrict__ wt,    // [64][128] bf16 W^T this layer
    const float* __restrict__ bl,             // [64]
    const float* __restrict__ g,              // [64] LN gamma (MODE 0)
    const float* __restrict__ bta,            // [64] LN beta  (MODE 0)
    unsigned short* __restrict__ hbout,       // [N,64] bf16 (MODE 0)
    float* __restrict__ out,                  // [N,64] fp32 (MODE 1)
    int N) {
    const int t = threadIdx.x;
    const int nbase = blockIdx.x * 64;
    const int wave = t >> 6;
    const int lane = t & 63;
    const int quad = lane >> 4;
    const int n16  = lane & 15;
    const int lbase = wave * 16;

    const int arow = min(nbase + lbase + n16, N - 1);   // clamp tail rows
    short8 af[4];
    af[0] = *(const short8*)(mean + (size_t)arow * DD + quad * 8);
    af[1] = *(const short8*)(mean + (size_t)arow * DD + 32 + quad * 8);
    af[2] = *(const short8*)(hbin + (size_t)arow * DD + quad * 8);
    af[3] = *(const short8*)(hbin + (size_t)arow * DD + 32 + quad * 8);

    f32x4 acc[4];
#pragma unroll
    for (int j = 0; j < 4; ++j) {
        float bv = bl[j * 16 + n16];
        acc[j] = (f32x4){bv, bv, bv, bv};
    }
#pragma unroll
    for (int s = 0; s < 4; ++s) {
#pragma unroll
        for (int j = 0; j < 4; ++j) {
            short8 bf = *(const short8*)(wt + (j * 16 + n16) * 128 + s * 32 + quad * 8);
            acc[j] = __builtin_amdgcn_mfma_f32_16x16x32_bf16(af[s], bf, acc[j], 0, 0, 0);
        }
    }

    float sg[4], sb[4];
    if (MODE == 0) {
#pragma unroll
        for (int j = 0; j < 4; ++j) { sg[j] = g[j * 16 + n16]; sb[j] = bta[j * 16 + n16]; }
    }

#pragma unroll
    for (int i = 0; i < 4; ++i) {
        const int lrow = lbase + quad * 4 + i;
        const int rr   = nbase + lrow;
        const int rrc  = min(rr, N - 1);
        float res[4];
#pragma unroll
        for (int j = 0; j < 4; ++j)
            res[j] = bf2f(hbin[(size_t)rrc * DD + j * 16 + n16]);
        float o[4];
        if (MODE == 0) {
            float s4 = acc[0][i] + acc[1][i] + acc[2][i] + acc[3][i];
            s4 += __shfl_xor(s4, 1, 64);
            s4 += __shfl_xor(s4, 2, 64);
            s4 += __shfl_xor(s4, 4, 64);
            s4 += __shfl_xor(s4, 8, 64);
            float mu = s4 * (1.0f / 64.0f);
            float d0 = acc[0][i] - mu, d1 = acc[1][i] - mu,
                  d2 = acc[2][i] - mu, d3 = acc[3][i] - mu;
            float qq = d0 * d0 + d1 * d1 + d2 * d2 + d3 * d3;
            qq += __shfl_xor(qq, 1, 64);
            qq += __shfl_xor(qq, 2, 64);
            qq += __shfl_xor(qq, 4, 64);
            qq += __shfl_xor(qq, 8, 64);
            float rstd = rsqrtf(qq * (1.0f / 64.0f) + 1e-5f);
            o[0] = fmaxf(d0 * rstd * sg[0] + sb[0], 0.f) + res[0];
            o[1] = fmaxf(d1 * rstd * sg[1] + sb[1], 0.f) + res[1];
            o[2] = fmaxf(d2 * rstd * sg[2] + sb[2], 0.f) + res[2];
            o[3] = fmaxf(d3 * rstd * sg[3] + sb[3], 0.f) + res[3];
        } else {
            o[0] = acc[0][i] + res[0];
            o[1] = acc[1][i] + res[1];
            o[2] = acc[2][i] + res[2];
            o[3] = acc[3][i] + res[3];
            float qq = o[0] * o[0] + o[1] * o[1] + o[2] * o[2] + o[3] * o[3];
            qq += __shfl_xor(qq, 1, 64);
            qq += __shfl_xor(qq, 2, 64);
            qq += __shfl_xor(qq, 4, 64);
            qq += __shfl_xor(qq, 8, 64);
            float inv = 1.0f / fmaxf(sqrtf(qq), 1e-12f);
            o[0] *= inv; o[1] *= inv; o[2] *= inv; o[3] *= inv;
        }
        if (rr < N) {
#pragma unroll
            for (int j = 0; j < 4; ++j) {
                if (MODE == 0)
                    hbout[(size_t)rr * DD + j * 16 + n16] = f2bf_rne(o[j]);
                else
                    out[(size_t)rr * DD + j * 16 + n16] = o[j];
            }
        }
    }
}

// ===========================================================================
extern "C" void kernel_launch(void* const* d_in, const int* in_sizes, int n_in,
                              void* d_out, int out_size, void* d_ws, size_t ws_size,
                              hipStream_t stream) {
    const float* x   = (const float*)d_in[0];
    const int*   ei  = (const int*)d_in[1];   // [2, E] int32: row0 = src, row1 = dst
    const float* Wl0 = (const float*)d_in[2];
    const float* bl0 = (const float*)d_in[3];
    const float* Wr0 = (const float*)d_in[4];
    const float* Wl1 = (const float*)d_in[5];
    const float* bl1 = (const float*)d_in[6];
    const float* Wr1 = (const float*)d_in[7];
    const float* Wl2 = (const float*)d_in[8];
    const float* bl2 = (const float*)d_in[9];
    const float* Wr2 = (const float*)d_in[10];
    const float* g0  = (const float*)d_in[11];
    const float* b0  = (const float*)d_in[12];
    const float* g1  = (const float*)d_in[13];
    const float* b1  = (const float*)d_in[14];

    const int N = in_sizes[0] / DD;   // 100000
    const int E = in_sizes[1] / 2;    // 1250000
    const int* src = ei;
    const int* dst = ei + E;

    const int nbkt  = (N + DBN - 1) >> DBSH;            // 782 dst-buckets
    const int ngr   = (N + (1 << GRSH) - 1) >> GRSH;    // 13 src granules
    const int nbins = nbkt * ngr;                       // 10166 sub-buckets

    // Workspace: buf int2[nbins<<8] (~20.8 MB) | HB0, HB1, MEAN bf16[N*64] |
    //            gCnt[nbins] | wtg bf16[3*8192]   (~59.3 MB total)
    int2* buf = (int2*)d_ws;
    unsigned short* HB0  = (unsigned short*)(buf + ((size_t)nbins << SCAPSH));
    unsigned short* HB1  = HB0 + (size_t)N * DD;
    unsigned short* MEAN = HB1 + (size_t)N * DD;
    int* gCnt = (int*)(MEAN + (size_t)N * DD);
    unsigned short* wtg =
        (unsigned short*)(((size_t)(gCnt + nbins) + 15) & ~(size_t)15);
    float* out = (float*)d_out;

    const int tiles = (N + 63) / 64;          // xform grid
    const int n4    = N * DD / 4;
    const int cgrid = (n4 + 255) / 256;
    const int bgrid = (E + 4095) / 4096;

    // ---- preprocessing: bf16 shadow + W^T tables + src-granule bucketing
    cvt_kernel<<<cgrid, 256, 0, stream>>>(x, HB0, n4, gCnt, nbins,
                                          Wl0, Wr0, Wl1, Wr1, Wl2, Wr2, wtg);
    bucket_kernel<<<bgrid, 1024, 0, stream>>>(src, dst, gCnt, buf, E, ngr);

    // ---- 3 layers: phase-aligned sweep (locality) + dense transform
    sweep_mean<<<nbkt, 256, 0, stream>>>(HB0, buf, gCnt, MEAN, N, ngr);
    sage_xform<0><<<tiles, 256, 0, stream>>>(HB0, MEAN, wtg,
                                             bl0, g0, b0, HB1, nullptr, N);
    sweep_mean<<<nbkt, 256, 0, stream>>>(HB1, buf, gCnt, MEAN, N, ngr);
    sage_xform<0><<<tiles, 256, 0, stream>>>(HB1, MEAN, wtg + 8192,
                                             bl1, g1, b1, HB0, nullptr, N);
    sweep_mean<<<nbkt, 256, 0, stream>>>(HB0, buf, gCnt, MEAN, N, ngr);
    sage_xform<1><<<tiles, 256, 0, stream>>>(HB0, MEAN, wtg + 16384,
                                             bl2, nullptr, nullptr, nullptr, out, N);
}

// Round 7
// 311.368 us; speedup vs baseline: 1.2162x; 1.2162x over previous
//
#include <hip/hip_runtime.h>

#define DD   64      // channels
#define BSH  9       // 512 nodes per dst bucket
#define BNODES 512
#define BCAPSH 13    // 8192 edges capacity per dst bucket (mean 6400 + 22 sigma)
#define GRSH 13      // src granule = 8192 nodes = 2 MB bf16 rows (fits per-XCD L2)
#define GRCAPSH 17   // 131072 edges capacity per granule region (mean 102K + 93 sigma)

typedef unsigned int uint32;
typedef __attribute__((ext_vector_type(8))) short short8;   // 8 bf16 (4 VGPRs)
typedef __attribute__((ext_vector_type(4))) float f32x4;    // MFMA accumulator

__device__ __forceinline__ unsigned short f2bf_rne(float f) {
    uint32 u = __float_as_uint(f);
    u += 0x7fffu + ((u >> 16) & 1u);   // round-to-nearest-even
    return (unsigned short)(u >> 16);
}
__device__ __forceinline__ float bf_lo(uint32 w) { return __uint_as_float(w << 16); }
__device__ __forceinline__ float bf_hi(uint32 w) { return __uint_as_float(w & 0xffff0000u); }
__device__ __forceinline__ float bf2f(unsigned short s) {
    return __uint_as_float(((uint32)s) << 16);
}

// ===========================================================================
// x (fp32) -> bf16 shadow; block 0 zeroes dst-bucket + granule counters;
// first 96 blocks also build the bf16 W^T tables for all 3 layers
// (wtg[layer][c*128+k], k<64 = Wl, k>=64 = Wr). Proven rounds 3-4.
// ===========================================================================
__global__ __launch_bounds__(256) void cvt_kernel(
    const float* __restrict__ x, unsigned short* __restrict__ xb, int n4,
    int* __restrict__ gCnt, int* __restrict__ gGr,
    const float* __restrict__ Wl0, const float* __restrict__ Wr0,
    const float* __restrict__ Wl1, const float* __restrict__ Wr1,
    const float* __restrict__ Wl2, const float* __restrict__ Wr2,
    unsigned short* __restrict__ wtg) {
    const int gid = blockIdx.x * 256 + threadIdx.x;
    if (blockIdx.x == 0) {
        gCnt[threadIdx.x] = 0;
        if (threadIdx.x < 16) gGr[threadIdx.x] = 0;
    }
    if (gid < 3 * 2 * DD * DD) {              // 24576 W^T elements
        int layer = gid >> 13;
        int idx   = gid & 8191;
        int k = idx >> 6, c = idx & 63;
        const float* Wsrc;
        if (layer == 0)      Wsrc = (k < DD) ? Wl0 : Wr0;
        else if (layer == 1) Wsrc = (k < DD) ? Wl1 : Wr1;
        else                 Wsrc = (k < DD) ? Wl2 : Wr2;
        float v = Wsrc[(k & (DD - 1)) * DD + c];
        wtg[layer * 8192 + c * 128 + k] = f2bf_rne(v);
    }
    if (gid < n4) {
        float4 v = ((const float4*)x)[gid];
        ushort4 p;
        p.x = f2bf_rne(v.x); p.y = f2bf_rne(v.y);
        p.z = f2bf_rne(v.z); p.w = f2bf_rne(v.w);
        ((ushort4*)xb)[gid] = p;
    }
}

// ===========================================================================
// Pass 0 (NEW): bucket edges by src>>13 into 13 granule regions. LDS
// histogram, ONE global atomic per (block,granule), region-local scatter
// (per-(block,granule) runs are contiguous -> coalesced-ish 8 B writes).
// Purpose: downstream dst-bucket/CSR scatters preserve approximate arrival
// order, so each node's neighbor list becomes ~granule-ascending. The
// dst-major gather then sweeps a moving ~2-granule (~4 MB) src window that
// fits per-XCD L2 -- turning its L3-rate random reads into L2 hits.
// Ordering is a locality heuristic only: mean is order-independent.
// ===========================================================================
__global__ __launch_bounds__(1024) void granule_kernel(
    const int* __restrict__ src, const int* __restrict__ dst,
    int* __restrict__ gGr, int2* __restrict__ gbuf, int E) {
    __shared__ int lc[16];
    __shared__ int lb[16];
    const int t = threadIdx.x;
    if (t < 16) lc[t] = 0;
    __syncthreads();

    const int e0 = blockIdx.x * 4096;
    int gk[4], rk[4], sv[4], dv[4];
#pragma unroll
    for (int k = 0; k < 4; ++k) {
        int e = e0 + k * 1024 + t;
        gk[k] = -1;
        if (e < E) {
            sv[k] = src[e];
            dv[k] = dst[e];
            gk[k] = sv[k] >> GRSH;
            rk[k] = atomicAdd(&lc[gk[k]], 1);
        }
    }
    __syncthreads();
    if (t < 16 && lc[t] > 0) lb[t] = atomicAdd(&gGr[t], lc[t]);
    __syncthreads();
#pragma unroll
    for (int k = 0; k < 4; ++k) {
        if (gk[k] >= 0) {
            int slot = lb[gk[k]] + rk[k];
            if (slot < (1 << GRCAPSH))        // 93-sigma margin; protects memory
                gbuf[((size_t)gk[k] << GRCAPSH) + slot] = make_int2(sv[k], dv[k]);
        }
    }
}

// ===========================================================================
// Pass 1: bucket edges by dst>>9 -- LDS histogram, one global atomic per
// (block,bucket), region-local scatter. Reads the granule-ordered stream
// (virtual index -> granule via 13-entry LDS prefix), so consecutive blocks
// carry ascending src granules into the dst buckets.
// ===========================================================================
__global__ __launch_bounds__(1024) void bucket_kernel(
    const int2* __restrict__ gbuf, const int* __restrict__ gGr,
    int* __restrict__ gCnt, int2* __restrict__ buf, int E, int ngr) {
    __shared__ int ldsCnt[256];
    __shared__ int base[256];
    __shared__ int pre[33];
    const int t = threadIdx.x;
    if (t < 256) ldsCnt[t] = 0;
    if (t == 0) {
        pre[0] = 0;
        for (int g = 0; g < ngr; ++g) {
            int c = gGr[g];
            pre[g + 1] = pre[g] + (c < (1 << GRCAPSH) ? c : (1 << GRCAPSH));
        }
    }
    __syncthreads();
    const int total = pre[ngr];

    const int e0 = blockIdx.x * 4096;
    int bk[4], rk[4], sv[4], dv[4];
#pragma unroll
    for (int k = 0; k < 4; ++k) {
        int e = e0 + k * 1024 + t;
        bk[k] = -1;
        if (e < total) {
            int g = 0;
            while (g < ngr - 1 && e >= pre[g + 1]) ++g;
            int2 ed = gbuf[((size_t)g << GRCAPSH) + (e - pre[g])];
            sv[k] = ed.x;
            dv[k] = ed.y;
            bk[k] = dv[k] >> BSH;
            rk[k] = atomicAdd(&ldsCnt[bk[k]], 1);
        }
    }
    __syncthreads();
    if (t < 256 && ldsCnt[t] > 0) base[t] = atomicAdd(&gCnt[t], ldsCnt[t]);
    __syncthreads();
#pragma unroll
    for (int k = 0; k < 4; ++k) {
        if (bk[k] >= 0) {
            int pos = (bk[k] << BCAPSH) + base[bk[k]] + rk[k];
            buf[pos] = make_int2(sv[k], dv[k]);
        }
    }
}

// ===========================================================================
// Pass 2: one block per bucket. Bucket base = masked wave reduction over
// gCnt; degree scan = __shfl_up wave scans + cross-wave combine. Scatter
// preserves approximate (granule-ascending) order into per-node CSR lists.
// ===========================================================================
__global__ __launch_bounds__(512) void csr_build(const int2* __restrict__ buf,
                                                 const int* __restrict__ gCnt,
                                                 int* __restrict__ offsets,
                                                 int* __restrict__ csr, int N, int E) {
    __shared__ int c1[BNODES];
    __shared__ int s2[BNODES];
    __shared__ int sw[16];
    const int b = blockIdx.x;
    const int t = threadIdx.x;
    const int lane = t & 63;
    const int w = t >> 6;

    // base = sum_{i<b} gCnt[i]  via masked butterfly reduction
    int gv = (t < 256 && t < b) ? gCnt[t] : 0;
#pragma unroll
    for (int d = 1; d < 64; d <<= 1) gv += __shfl_xor(gv, d, 64);
    if (lane == 0) sw[w] = gv;        // waves 4..7 contribute 0
    c1[t] = 0;
    __syncthreads();
    int base = 0;
#pragma unroll
    for (int i = 0; i < 8; ++i) base += sw[i];

    const int cnt = gCnt[b];
    const int2* bb = buf + ((size_t)b << BCAPSH);
    for (int i = t; i < cnt; i += 512) atomicAdd(&c1[bb[i].y & (BNODES - 1)], 1);
    __syncthreads();

    // inclusive scan of the 512 per-node counts: wave scan + cross-wave
    int v = c1[t];
    int x = v;
#pragma unroll
    for (int d = 1; d < 64; d <<= 1) {
        int y = __shfl_up(x, d, 64);
        if (lane >= d) x += y;
    }
    if (lane == 63) sw[8 + w] = x;
    __syncthreads();
    int woff = 0;
    for (int i = 0; i < w; ++i) woff += sw[8 + i];
    int excl = x + woff - v;

    const int node = (b << BSH) + t;
    if (node < N) offsets[node] = base + excl;
    if (b == 0 && t == 0) offsets[N] = E;

    s2[t] = excl;
    c1[t] = 0;
    __syncthreads();

    for (int i = t; i < cnt; i += 512) {
        int2 e = bb[i];
        int d = e.y & (BNODES - 1);
        int r = atomicAdd(&c1[d], 1);
        csr[base + s2[d] + r] = e.x;
    }
}

// ===========================================================================
// Gather kernel: pure neighbor-mean, byte-identical compute to round 4.
// 8 lanes/node, 8-deep load batches, zero LDS. (256,4) allocator mode ->
// ~52 VGPR, no spill, 8 blocks/CU. Neighbor lists are now ~granule-sorted,
// so the resident block set reads from a moving L2-size src window.
// ===========================================================================
__global__ __launch_bounds__(256, 4) void gather_mean(
    const unsigned short* __restrict__ hbin,  // [N,64] bf16 layer input
    const int* __restrict__ offsets,          // [N+1]
    const int* __restrict__ csr,              // [E]
    unsigned short* __restrict__ mean,        // [N,64] bf16 out
    int N) {
    const int grp  = threadIdx.x >> 3;        // 0..31: node within block
    const int q    = threadIdx.x & 7;         // 16 B chunk within 128 B row
    const int node = blockIdx.x * 32 + grp;
    if (node >= N) return;

    const int off0 = offsets[node];
    const int off1 = offsets[node + 1];
    const int deg  = off1 - off0;

    float a0 = 0.f, a1 = 0.f, a2 = 0.f, a3 = 0.f,
          a4 = 0.f, a5 = 0.f, a6 = 0.f, a7 = 0.f;
#pragma unroll 1
    for (int j = off0; j < off1; j += 8) {
        uint4 v[8];
#pragma unroll
        for (int s = 0; s < 8; ++s) {
            uint4 tt = make_uint4(0u, 0u, 0u, 0u);
            int idx = j + s;
            if (idx < off1) {
                int sn = __builtin_nontemporal_load(&csr[idx]);
                tt = ((const uint4*)(hbin + (size_t)sn * DD))[q];
            }
            v[s] = tt;
        }
#pragma unroll
        for (int s = 0; s < 8; ++s) {
            a0 += bf_lo(v[s].x); a1 += bf_hi(v[s].x);
            a2 += bf_lo(v[s].y); a3 += bf_hi(v[s].y);
            a4 += bf_lo(v[s].z); a5 += bf_hi(v[s].z);
            a6 += bf_lo(v[s].w); a7 += bf_hi(v[s].w);
        }
    }
    float invd = 1.0f / fmaxf((float)deg, 1.0f);
    uint4 wv;
    wv.x = (uint32)f2bf_rne(a0 * invd) | ((uint32)f2bf_rne(a1 * invd) << 16);
    wv.y = (uint32)f2bf_rne(a2 * invd) | ((uint32)f2bf_rne(a3 * invd) << 16);
    wv.z = (uint32)f2bf_rne(a4 * invd) | ((uint32)f2bf_rne(a5 * invd) << 16);
    wv.w = (uint32)f2bf_rne(a6 * invd) | ((uint32)f2bf_rne(a7 * invd) << 16);
    *(uint4*)(mean + (size_t)node * DD + q * 8) = wv;   // coalesced 128 B/node
}

// ===========================================================================
// Transform kernel: y = [mean||self] @ [Wl;Wr] + bl, then
//   MODE 0: hbout = bf16(relu(LN(y)) + self);  MODE 1: out = l2norm(y+self).
// Dense streaming, zero LDS, zero barriers (proven round 4).
// Block = 256 thr = 4 waves = 64 nodes. C/D: col=lane&15, row=quad*4+reg.
// ===========================================================================
template <int MODE>
__global__ __launch_bounds__(256, 4) void sage_xform(
    const unsigned short* __restrict__ hbin,  // [N,64] bf16 self
    const unsigned short* __restrict__ mean,  // [N,64] bf16 neighbor mean
    const unsigned short* __restrict__ wt,    // [64][128] bf16 W^T this layer
    const float* __restrict__ bl,             // [64]
    const float* __restrict__ g,              // [64] LN gamma (MODE 0)
    const float* __restrict__ bta,            // [64] LN beta  (MODE 0)
    unsigned short* __restrict__ hbout,       // [N,64] bf16 (MODE 0)
    float* __restrict__ out,                  // [N,64] fp32 (MODE 1)
    int N) {
    const int t = threadIdx.x;
    const int nbase = blockIdx.x * 64;
    const int wave = t >> 6;
    const int lane = t & 63;
    const int quad = lane >> 4;
    const int n16  = lane & 15;
    const int lbase = wave * 16;

    const int arow = min(nbase + lbase + n16, N - 1);   // clamp tail rows
    short8 af[4];
    af[0] = *(const short8*)(mean + (size_t)arow * DD + quad * 8);
    af[1] = *(const short8*)(mean + (size_t)arow * DD + 32 + quad * 8);
    af[2] = *(const short8*)(hbin + (size_t)arow * DD + quad * 8);
    af[3] = *(const short8*)(hbin + (size_t)arow * DD + 32 + quad * 8);

    f32x4 acc[4];
#pragma unroll
    for (int j = 0; j < 4; ++j) {
        float bv = bl[j * 16 + n16];
        acc[j] = (f32x4){bv, bv, bv, bv};
    }
#pragma unroll
    for (int s = 0; s < 4; ++s) {
#pragma unroll
        for (int j = 0; j < 4; ++j) {
            short8 bf = *(const short8*)(wt + (j * 16 + n16) * 128 + s * 32 + quad * 8);
            acc[j] = __builtin_amdgcn_mfma_f32_16x16x32_bf16(af[s], bf, acc[j], 0, 0, 0);
        }
    }

    float sg[4], sb[4];
    if (MODE == 0) {
#pragma unroll
        for (int j = 0; j < 4; ++j) { sg[j] = g[j * 16 + n16]; sb[j] = bta[j * 16 + n16]; }
    }

#pragma unroll
    for (int i = 0; i < 4; ++i) {
        const int lrow = lbase + quad * 4 + i;
        const int rr   = nbase + lrow;
        const int rrc  = min(rr, N - 1);
        float res[4];
#pragma unroll
        for (int j = 0; j < 4; ++j)
            res[j] = bf2f(hbin[(size_t)rrc * DD + j * 16 + n16]);
        float o[4];
        if (MODE == 0) {
            float s4 = acc[0][i] + acc[1][i] + acc[2][i] + acc[3][i];
            s4 += __shfl_xor(s4, 1, 64);
            s4 += __shfl_xor(s4, 2, 64);
            s4 += __shfl_xor(s4, 4, 64);
            s4 += __shfl_xor(s4, 8, 64);
            float mu = s4 * (1.0f / 64.0f);
            float d0 = acc[0][i] - mu, d1 = acc[1][i] - mu,
                  d2 = acc[2][i] - mu, d3 = acc[3][i] - mu;
            float qq = d0 * d0 + d1 * d1 + d2 * d2 + d3 * d3;
            qq += __shfl_xor(qq, 1, 64);
            qq += __shfl_xor(qq, 2, 64);
            qq += __shfl_xor(qq, 4, 64);
            qq += __shfl_xor(qq, 8, 64);
            float rstd = rsqrtf(qq * (1.0f / 64.0f) + 1e-5f);
            o[0] = fmaxf(d0 * rstd * sg[0] + sb[0], 0.f) + res[0];
            o[1] = fmaxf(d1 * rstd * sg[1] + sb[1], 0.f) + res[1];
            o[2] = fmaxf(d2 * rstd * sg[2] + sb[2], 0.f) + res[2];
            o[3] = fmaxf(d3 * rstd * sg[3] + sb[3], 0.f) + res[3];
        } else {
            o[0] = acc[0][i] + res[0];
            o[1] = acc[1][i] + res[1];
            o[2] = acc[2][i] + res[2];
            o[3] = acc[3][i] + res[3];
            float qq = o[0] * o[0] + o[1] * o[1] + o[2] * o[2] + o[3] * o[3];
            qq += __shfl_xor(qq, 1, 64);
            qq += __shfl_xor(qq, 2, 64);
            qq += __shfl_xor(qq, 4, 64);
            qq += __shfl_xor(qq, 8, 64);
            float inv = 1.0f / fmaxf(sqrtf(qq), 1e-12f);
            o[0] *= inv; o[1] *= inv; o[2] *= inv; o[3] *= inv;
        }
        if (rr < N) {
#pragma unroll
            for (int j = 0; j < 4; ++j) {
                if (MODE == 0)
                    hbout[(size_t)rr * DD + j * 16 + n16] = f2bf_rne(o[j]);
                else
                    out[(size_t)rr * DD + j * 16 + n16] = o[j];
            }
        }
    }
}

// ===========================================================================
extern "C" void kernel_launch(void* const* d_in, const int* in_sizes, int n_in,
                              void* d_out, int out_size, void* d_ws, size_t ws_size,
                              hipStream_t stream) {
    const float* x   = (const float*)d_in[0];
    const int*   ei  = (const int*)d_in[1];   // [2, E] int32: row0 = src, row1 = dst
    const float* Wl0 = (const float*)d_in[2];
    const float* bl0 = (const float*)d_in[3];
    const float* Wr0 = (const float*)d_in[4];
    const float* Wl1 = (const float*)d_in[5];
    const float* bl1 = (const float*)d_in[6];
    const float* Wr1 = (const float*)d_in[7];
    const float* Wl2 = (const float*)d_in[8];
    const float* bl2 = (const float*)d_in[9];
    const float* Wr2 = (const float*)d_in[10];
    const float* g0  = (const float*)d_in[11];
    const float* b0  = (const float*)d_in[12];
    const float* g1  = (const float*)d_in[13];
    const float* b1  = (const float*)d_in[14];

    const int N = in_sizes[0] / DD;   // 100000
    const int E = in_sizes[1] / 2;    // 1250000
    const int* src = ei;
    const int* dst = ei + E;
    const int NB  = (N + BNODES - 1) >> BSH;            // 196 dst buckets
    const int ngr = (N + (1 << GRSH) - 1) >> GRSH;      // 13 src granules

    // Workspace: gbuf int2[ngr<<17] (~13.6 MB) | bucketBuf int2[256<<13]
    //   (16.8 MB) | HB0, HB1, MEAN bf16[N*64] | csr[E] | offsets[N+1] |
    //   gCnt[256] | gGr[16] | wtg bf16[3*8192]   (~76 MB)
    int2* gbuf      = (int2*)d_ws;
    int2* bucketBuf = gbuf + ((size_t)ngr << GRCAPSH);
    unsigned short* HB0  = (unsigned short*)(bucketBuf + ((size_t)256 << BCAPSH));
    unsigned short* HB1  = HB0 + (size_t)N * DD;
    unsigned short* MEAN = HB1 + (size_t)N * DD;
    int*   csr     = (int*)(MEAN + (size_t)N * DD);
    int*   offsets = csr + E;
    int*   gCnt    = offsets + (N + 1);
    int*   gGr     = gCnt + 256;
    unsigned short* wtg =
        (unsigned short*)(((size_t)(gGr + 16) + 15) & ~(size_t)15);
    float* out     = (float*)d_out;

    const int tiles = (N + 63) / 64;          // xform grid
    const int ggrid = (N + 31) / 32;          // gather grid
    const int n4    = N * DD / 4;
    const int cgrid = (n4 + 255) / 256;
    const int bgrid = (E + 4095) / 4096;

    // ---- preprocessing: bf16 shadow + W^T; granule sort; dst bucket; CSR
    cvt_kernel<<<cgrid, 256, 0, stream>>>(x, HB0, n4, gCnt, gGr,
                                          Wl0, Wr0, Wl1, Wr1, Wl2, Wr2, wtg);
    granule_kernel<<<bgrid, 1024, 0, stream>>>(src, dst, gGr, gbuf, E);
    bucket_kernel<<<bgrid, 1024, 0, stream>>>(gbuf, gGr, gCnt, bucketBuf, E, ngr);
    csr_build<<<NB, 512, 0, stream>>>(bucketBuf, gCnt, offsets, csr, N, E);

    // ---- 3 layers: gather (L2-window sweep) + transform (dense streaming)
    gather_mean<<<ggrid, 256, 0, stream>>>(HB0, offsets, csr, MEAN, N);
    sage_xform<0><<<tiles, 256, 0, stream>>>(HB0, MEAN, wtg,
                                             bl0, g0, b0, HB1, nullptr, N);
    gather_mean<<<ggrid, 256, 0, stream>>>(HB1, offsets, csr, MEAN, N);
    sage_xform<0><<<tiles, 256, 0, stream>>>(HB1, MEAN, wtg + 8192,
                                             bl1, g1, b1, HB0, nullptr, N);
    gather_mean<<<ggrid, 256, 0, stream>>>(HB0, offsets, csr, MEAN, N);
    sage_xform<1><<<tiles, 256, 0, stream>>>(HB0, MEAN, wtg + 16384,
                                             bl2, nullptr, nullptr, nullptr, out, N);
}

// Round 8
// 304.812 us; speedup vs baseline: 1.2423x; 1.0215x over previous
//
#include <hip/hip_runtime.h>

#define DD   64      // channels
#define BSH  9       // 512 nodes per bucket
#define BNODES 512
#define BCAPSH 13    // 8192 edges capacity per bucket (mean 6400 + 22 sigma)

typedef unsigned int uint32;
typedef __attribute__((ext_vector_type(8))) short short8;   // 8 bf16 (4 VGPRs)
typedef __attribute__((ext_vector_type(4))) float f32x4;    // MFMA accumulator

__device__ __forceinline__ unsigned short f2bf_rne(float f) {
    uint32 u = __float_as_uint(f);
    u += 0x7fffu + ((u >> 16) & 1u);   // round-to-nearest-even
    return (unsigned short)(u >> 16);
}
__device__ __forceinline__ float bf_lo(uint32 w) { return __uint_as_float(w << 16); }
__device__ __forceinline__ float bf_hi(uint32 w) { return __uint_as_float(w & 0xffff0000u); }
__device__ __forceinline__ float bf2f(unsigned short s) {
    return __uint_as_float(((uint32)s) << 16);
}

// ===========================================================================
// x (fp32) -> bf16 shadow; block 0 zeroes bucket counters; first 96 blocks
// also build the bf16 W^T tables for all 3 layers (wtg[layer][c*128+k],
// k<64 = Wl, k>=64 = Wr). Proven rounds 3-4.
// ===========================================================================
__global__ __launch_bounds__(256) void cvt_kernel(
    const float* __restrict__ x, unsigned short* __restrict__ xb, int n4,
    int* __restrict__ gCnt,
    const float* __restrict__ Wl0, const float* __restrict__ Wr0,
    const float* __restrict__ Wl1, const float* __restrict__ Wr1,
    const float* __restrict__ Wl2, const float* __restrict__ Wr2,
    unsigned short* __restrict__ wtg) {
    const int gid = blockIdx.x * 256 + threadIdx.x;
    if (blockIdx.x == 0) gCnt[threadIdx.x] = 0;
    if (gid < 3 * 2 * DD * DD) {              // 24576 W^T elements
        int layer = gid >> 13;
        int idx   = gid & 8191;
        int k = idx >> 6, c = idx & 63;
        const float* Wsrc;
        if (layer == 0)      Wsrc = (k < DD) ? Wl0 : Wr0;
        else if (layer == 1) Wsrc = (k < DD) ? Wl1 : Wr1;
        else                 Wsrc = (k < DD) ? Wl2 : Wr2;
        float v = Wsrc[(k & (DD - 1)) * DD + c];
        wtg[layer * 8192 + c * 128 + k] = f2bf_rne(v);
    }
    if (gid < n4) {
        float4 v = ((const float4*)x)[gid];
        ushort4 p;
        p.x = f2bf_rne(v.x); p.y = f2bf_rne(v.y);
        p.z = f2bf_rne(v.z); p.w = f2bf_rne(v.w);
        ((ushort4*)xb)[gid] = p;
    }
}

// ===========================================================================
// Pass 1: bucket edges by dst>>9 -- LDS histogram, ONE global atomic per
// (block,bucket), region-local scatter. (Round 5's per-edge global-atomic
// variant with 8 B scattered stores cost 85 us from write amplification;
// this LDS-aggregated version is ~12 us.)
// ===========================================================================
__global__ __launch_bounds__(1024) void bucket_kernel(const int* __restrict__ src,
                                                      const int* __restrict__ dst,
                                                      int* __restrict__ gCnt,
                                                      int2* __restrict__ buf, int E) {
    __shared__ int ldsCnt[256];
    __shared__ int base[256];
    const int t = threadIdx.x;
    if (t < 256) ldsCnt[t] = 0;
    __syncthreads();

    const int e0 = blockIdx.x * 4096;
    int bk[4], rk[4], sv[4], dv[4];
#pragma unroll
    for (int k = 0; k < 4; ++k) {
        int e = e0 + k * 1024 + t;
        bk[k] = -1;
        if (e < E) {
            dv[k] = dst[e];
            sv[k] = src[e];
            bk[k] = dv[k] >> BSH;
            rk[k] = atomicAdd(&ldsCnt[bk[k]], 1);
        }
    }
    __syncthreads();
    if (t < 256 && ldsCnt[t] > 0) base[t] = atomicAdd(&gCnt[t], ldsCnt[t]);
    __syncthreads();
#pragma unroll
    for (int k = 0; k < 4; ++k) {
        if (bk[k] >= 0) {
            int pos = (bk[k] << BCAPSH) + base[bk[k]] + rk[k];
            buf[pos] = make_int2(sv[k], dv[k]);
        }
    }
}

// ===========================================================================
// Pass 2: one block per bucket. Bucket base = masked wave reduction over
// gCnt; degree scan = __shfl_up wave scans + cross-wave combine.
// ===========================================================================
__global__ __launch_bounds__(512) void csr_build(const int2* __restrict__ buf,
                                                 const int* __restrict__ gCnt,
                                                 int* __restrict__ offsets,
                                                 int* __restrict__ csr, int N, int E) {
    __shared__ int c1[BNODES];
    __shared__ int s2[BNODES];
    __shared__ int sw[16];
    const int b = blockIdx.x;
    const int t = threadIdx.x;
    const int lane = t & 63;
    const int w = t >> 6;

    // base = sum_{i<b} gCnt[i]  via masked butterfly reduction
    int gv = (t < 256 && t < b) ? gCnt[t] : 0;
#pragma unroll
    for (int d = 1; d < 64; d <<= 1) gv += __shfl_xor(gv, d, 64);
    if (lane == 0) sw[w] = gv;        // waves 4..7 contribute 0
    c1[t] = 0;
    __syncthreads();
    int base = 0;
#pragma unroll
    for (int i = 0; i < 8; ++i) base += sw[i];

    const int cnt = gCnt[b];
    const int2* bb = buf + ((size_t)b << BCAPSH);
    for (int i = t; i < cnt; i += 512) atomicAdd(&c1[bb[i].y & (BNODES - 1)], 1);
    __syncthreads();

    // inclusive scan of the 512 per-node counts: wave scan + cross-wave
    int v = c1[t];
    int x = v;
#pragma unroll
    for (int d = 1; d < 64; d <<= 1) {
        int y = __shfl_up(x, d, 64);
        if (lane >= d) x += y;
    }
    if (lane == 63) sw[8 + w] = x;
    __syncthreads();
    int woff = 0;
    for (int i = 0; i < w; ++i) woff += sw[8 + i];
    int excl = x + woff - v;

    const int node = (b << BSH) + t;
    if (node < N) offsets[node] = base + excl;
    if (b == 0 && t == 0) offsets[N] = E;

    s2[t] = excl;
    c1[t] = 0;
    __syncthreads();

    for (int i = t; i < cnt; i += 512) {
        int2 e = bb[i];
        int d = e.y & (BNODES - 1);
        int r = atomicAdd(&c1[d], 1);
        csr[base + s2[d] + r] = e.x;
    }
}

// ===========================================================================
// Gather kernel: pure neighbor-mean. 8 lanes/node, 8-deep load batches,
// ZERO LDS, no MFMA, no epilogue state. (256,4) allocator mode -> ~52 VGPR,
// no spill, full 8-deep memory-level parallelism. This kernel sits at the
// measured random-access throughput floor (~160 MB of random 128 B row
// reads / layer at ~3.3 TB/s through L2/L3): occupancy doubling (r4),
// scatter-accumulate (r5), and src-granule ordering (r7) all failed to
// move it. Do not touch without a fundamentally different data layout.
// ===========================================================================
__global__ __launch_bounds__(256, 4) void gather_mean(
    const unsigned short* __restrict__ hbin,  // [N,64] bf16 layer input
    const int* __restrict__ offsets,          // [N+1]
    const int* __restrict__ csr,              // [E]
    unsigned short* __restrict__ mean,        // [N,64] bf16 out
    int N) {
    const int grp  = threadIdx.x >> 3;        // 0..31: node within block
    const int q    = threadIdx.x & 7;         // 16 B chunk within 128 B row
    const int node = blockIdx.x * 32 + grp;
    if (node >= N) return;

    const int off0 = offsets[node];
    const int off1 = offsets[node + 1];
    const int deg  = off1 - off0;

    float a0 = 0.f, a1 = 0.f, a2 = 0.f, a3 = 0.f,
          a4 = 0.f, a5 = 0.f, a6 = 0.f, a7 = 0.f;
#pragma unroll 1
    for (int j = off0; j < off1; j += 8) {
        uint4 v[8];
#pragma unroll
        for (int s = 0; s < 8; ++s) {
            uint4 tt = make_uint4(0u, 0u, 0u, 0u);
            int idx = j + s;
            if (idx < off1) {
                int sn = __builtin_nontemporal_load(&csr[idx]);
                tt = ((const uint4*)(hbin + (size_t)sn * DD))[q];
            }
            v[s] = tt;
        }
#pragma unroll
        for (int s = 0; s < 8; ++s) {
            a0 += bf_lo(v[s].x); a1 += bf_hi(v[s].x);
            a2 += bf_lo(v[s].y); a3 += bf_hi(v[s].y);
            a4 += bf_lo(v[s].z); a5 += bf_hi(v[s].z);
            a6 += bf_lo(v[s].w); a7 += bf_hi(v[s].w);
        }
    }
    float invd = 1.0f / fmaxf((float)deg, 1.0f);
    uint4 wv;
    wv.x = (uint32)f2bf_rne(a0 * invd) | ((uint32)f2bf_rne(a1 * invd) << 16);
    wv.y = (uint32)f2bf_rne(a2 * invd) | ((uint32)f2bf_rne(a3 * invd) << 16);
    wv.z = (uint32)f2bf_rne(a4 * invd) | ((uint32)f2bf_rne(a5 * invd) << 16);
    wv.w = (uint32)f2bf_rne(a6 * invd) | ((uint32)f2bf_rne(a7 * invd) << 16);
    *(uint4*)(mean + (size_t)node * DD + q * 8) = wv;   // coalesced 128 B/node
}

// ===========================================================================
// Transform kernel: y = [mean||self] @ [Wl;Wr] + bl, then
//   MODE 0: hbout = bf16(relu(LN(y)) + self);  MODE 1: out = l2norm(y+self).
// Dense streaming, zero LDS, zero barriers (proven round 4).
// Block = 256 thr = 4 waves = 64 nodes. C/D: col=lane&15, row=quad*4+reg.
// ===========================================================================
template <int MODE>
__global__ __launch_bounds__(256, 4) void sage_xform(
    const unsigned short* __restrict__ hbin,  // [N,64] bf16 self
    const unsigned short* __restrict__ mean,  // [N,64] bf16 neighbor mean
    const unsigned short* __restrict__ wt,    // [64][128] bf16 W^T this layer
    const float* __restrict__ bl,             // [64]
    const float* __restrict__ g,              // [64] LN gamma (MODE 0)
    const float* __restrict__ bta,            // [64] LN beta  (MODE 0)
    unsigned short* __restrict__ hbout,       // [N,64] bf16 (MODE 0)
    float* __restrict__ out,                  // [N,64] fp32 (MODE 1)
    int N) {
    const int t = threadIdx.x;
    const int nbase = blockIdx.x * 64;
    const int wave = t >> 6;
    const int lane = t & 63;
    const int quad = lane >> 4;
    const int n16  = lane & 15;
    const int lbase = wave * 16;

    const int arow = min(nbase + lbase + n16, N - 1);   // clamp tail rows
    short8 af[4];
    af[0] = *(const short8*)(mean + (size_t)arow * DD + quad * 8);
    af[1] = *(const short8*)(mean + (size_t)arow * DD + 32 + quad * 8);
    af[2] = *(const short8*)(hbin + (size_t)arow * DD + quad * 8);
    af[3] = *(const short8*)(hbin + (size_t)arow * DD + 32 + quad * 8);

    f32x4 acc[4];
#pragma unroll
    for (int j = 0; j < 4; ++j) {
        float bv = bl[j * 16 + n16];
        acc[j] = (f32x4){bv, bv, bv, bv};
    }
#pragma unroll
    for (int s = 0; s < 4; ++s) {
#pragma unroll
        for (int j = 0; j < 4; ++j) {
            short8 bf = *(const short8*)(wt + (j * 16 + n16) * 128 + s * 32 + quad * 8);
            acc[j] = __builtin_amdgcn_mfma_f32_16x16x32_bf16(af[s], bf, acc[j], 0, 0, 0);
        }
    }

    float sg[4], sb[4];
    if (MODE == 0) {
#pragma unroll
        for (int j = 0; j < 4; ++j) { sg[j] = g[j * 16 + n16]; sb[j] = bta[j * 16 + n16]; }
    }

#pragma unroll
    for (int i = 0; i < 4; ++i) {
        const int lrow = lbase + quad * 4 + i;
        const int rr   = nbase + lrow;
        const int rrc  = min(rr, N - 1);
        float res[4];
#pragma unroll
        for (int j = 0; j < 4; ++j)
            res[j] = bf2f(hbin[(size_t)rrc * DD + j * 16 + n16]);
        float o[4];
        if (MODE == 0) {
            float s4 = acc[0][i] + acc[1][i] + acc[2][i] + acc[3][i];
            s4 += __shfl_xor(s4, 1, 64);
            s4 += __shfl_xor(s4, 2, 64);
            s4 += __shfl_xor(s4, 4, 64);
            s4 += __shfl_xor(s4, 8, 64);
            float mu = s4 * (1.0f / 64.0f);
            float d0 = acc[0][i] - mu, d1 = acc[1][i] - mu,
                  d2 = acc[2][i] - mu, d3 = acc[3][i] - mu;
            float qq = d0 * d0 + d1 * d1 + d2 * d2 + d3 * d3;
            qq += __shfl_xor(qq, 1, 64);
            qq += __shfl_xor(qq, 2, 64);
            qq += __shfl_xor(qq, 4, 64);
            qq += __shfl_xor(qq, 8, 64);
            float rstd = rsqrtf(qq * (1.0f / 64.0f) + 1e-5f);
            o[0] = fmaxf(d0 * rstd * sg[0] + sb[0], 0.f) + res[0];
            o[1] = fmaxf(d1 * rstd * sg[1] + sb[1], 0.f) + res[1];
            o[2] = fmaxf(d2 * rstd * sg[2] + sb[2], 0.f) + res[2];
            o[3] = fmaxf(d3 * rstd * sg[3] + sb[3], 0.f) + res[3];
        } else {
            o[0] = acc[0][i] + res[0];
            o[1] = acc[1][i] + res[1];
            o[2] = acc[2][i] + res[2];
            o[3] = acc[3][i] + res[3];
            float qq = o[0] * o[0] + o[1] * o[1] + o[2] * o[2] + o[3] * o[3];
            qq += __shfl_xor(qq, 1, 64);
            qq += __shfl_xor(qq, 2, 64);
            qq += __shfl_xor(qq, 4, 64);
            qq += __shfl_xor(qq, 8, 64);
            float inv = 1.0f / fmaxf(sqrtf(qq), 1e-12f);
            o[0] *= inv; o[1] *= inv; o[2] *= inv; o[3] *= inv;
        }
        if (rr < N) {
#pragma unroll
            for (int j = 0; j < 4; ++j) {
                if (MODE == 0)
                    hbout[(size_t)rr * DD + j * 16 + n16] = f2bf_rne(o[j]);
                else
                    out[(size_t)rr * DD + j * 16 + n16] = o[j];
            }
        }
    }
}

// ===========================================================================
extern "C" void kernel_launch(void* const* d_in, const int* in_sizes, int n_in,
                              void* d_out, int out_size, void* d_ws, size_t ws_size,
                              hipStream_t stream) {
    const float* x   = (const float*)d_in[0];
    const int*   ei  = (const int*)d_in[1];   // [2, E] int32: row0 = src, row1 = dst
    const float* Wl0 = (const float*)d_in[2];
    const float* bl0 = (const float*)d_in[3];
    const float* Wr0 = (const float*)d_in[4];
    const float* Wl1 = (const float*)d_in[5];
    const float* bl1 = (const float*)d_in[6];
    const float* Wr1 = (const float*)d_in[7];
    const float* Wl2 = (const float*)d_in[8];
    const float* bl2 = (const float*)d_in[9];
    const float* Wr2 = (const float*)d_in[10];
    const float* g0  = (const float*)d_in[11];
    const float* b0  = (const float*)d_in[12];
    const float* g1  = (const float*)d_in[13];
    const float* b1  = (const float*)d_in[14];

    const int N = in_sizes[0] / DD;   // 100000
    const int E = in_sizes[1] / 2;    // 1250000
    const int* src = ei;
    const int* dst = ei + E;
    const int NB = (N + BNODES - 1) >> BSH;   // 196 buckets

    // Workspace: bucketBuf int2[256<<13] | HB0, HB1, MEAN bf16[N*64] |
    //            csr[E] | offsets[N+1] | gCnt[256] | wtg bf16[3*8192]
    int2* bucketBuf = (int2*)d_ws;
    unsigned short* HB0  = (unsigned short*)(bucketBuf + ((size_t)256 << BCAPSH));
    unsigned short* HB1  = HB0 + (size_t)N * DD;
    unsigned short* MEAN = HB1 + (size_t)N * DD;
    int*   csr     = (int*)(MEAN + (size_t)N * DD);
    int*   offsets = csr + E;
    int*   gCnt    = offsets + (N + 1);
    unsigned short* wtg =
        (unsigned short*)(((size_t)(gCnt + 256) + 15) & ~(size_t)15);
    float* out     = (float*)d_out;

    const int tiles  = (N + 63) / 64;         // xform grid
    const int ggrid  = (N + 31) / 32;         // gather grid
    const int n4     = N * DD / 4;
    const int cgrid  = (n4 + 255) / 256;
    const int bgrid  = (E + 4095) / 4096;

    // ---- CSR build: bucket counting sort (graph static across layers)
    cvt_kernel<<<cgrid, 256, 0, stream>>>(x, HB0, n4, gCnt,
                                          Wl0, Wr0, Wl1, Wr1, Wl2, Wr2, wtg);
    bucket_kernel<<<bgrid, 1024, 0, stream>>>(src, dst, gCnt, bucketBuf, E);
    csr_build<<<NB, 512, 0, stream>>>(bucketBuf, gCnt, offsets, csr, N, E);

    // ---- 3 layers: gather (latency-optimized) + transform (dense streaming)
    gather_mean<<<ggrid, 256, 0, stream>>>(HB0, offsets, csr, MEAN, N);
    sage_xform<0><<<tiles, 256, 0, stream>>>(HB0, MEAN, wtg,
                                             bl0, g0, b0, HB1, nullptr, N);
    gather_mean<<<ggrid, 256, 0, stream>>>(HB1, offsets, csr, MEAN, N);
    sage_xform<0><<<tiles, 256, 0, stream>>>(HB1, MEAN, wtg + 8192,
                                             bl1, g1, b1, HB0, nullptr, N);
    gather_mean<<<ggrid, 256, 0, stream>>>(HB0, offsets, csr, MEAN, N);
    sage_xform<1><<<tiles, 256, 0, stream>>>(HB0, MEAN, wtg + 16384,
                                             bl2, nullptr, nullptr, nullptr, out, N);
}